// Round 9
// baseline (187.822 us; speedup 1.0000x reference)
//
#include <hip/hip_runtime.h>
#include <math.h>

constexpr int H = 512, W = 512;
constexpr int N_ANGLES = 360;
constexpr int N_DET = 736;
constexpr int N_STEPS = 725;                 // ceil(hypot(512,512))
constexpr int SINO_SIZE = N_ANGLES * N_DET;  // 264960

constexpr int DET_TILE = 64;
constexpr int K_TILE   = 64;
constexpr int PITCH    = 106;  // dword cells; even; 106 mod 32 = 10
constexpr int ROWS     = 94;
constexpr int CHUNKS   = PITCH / 2;          // 53 cell-pairs per row
// LDS: 94*106*4 = 39856 B -> 4 blocks/CU @ 512 thr = 32 waves/CU

typedef float v2f __attribute__((ext_vector_type(2)));
typedef __fp16 h2f __attribute__((ext_vector_type(2)));   // matches cvt_pkrtz return type
union PackU { unsigned u; h2f h; };

// ---------------------------------------------------------------------------
// Kernel 1: updated_reco = x + reco
// ---------------------------------------------------------------------------
__global__ void add_kernel(const float4* __restrict__ x,
                           const float4* __restrict__ reco,
                           float4* __restrict__ out) {
    int i = blockIdx.x * blockDim.x + threadIdx.x;
    float4 a = x[i];
    float4 b = reco[i];
    out[i] = make_float4(a.x + b.x, a.y + b.y, a.z + b.z, a.w + b.w);
}

// ---------------------------------------------------------------------------
// Kernel 2: forward projection with f16 vertical-pair LDS tiles.
// Cell (r, x) = pack_f16x2(img[y0+r][x], img[y0+r+1][x])  (0 outside image).
// A bilinear sample reads ONE ds_read2_b32 (dwords idx, idx+1):
//   dword0 = (v00, v10), dword1 = (v01, v11)  -> packed-f32 lerp.
// Halves LDS dword traffic vs f32 tiles (round-7 postmortem: LDS-pipe bound).
// Block = (angle, 64 detectors), 512 threads; wave footprint 16 det x 4 k.
// ---------------------------------------------------------------------------
__global__ __launch_bounds__(512, 8) void radon_kernel(const float* __restrict__ img,
                                                       const float* __restrict__ angles,
                                                       float* __restrict__ sino) {
    __shared__ unsigned tile[ROWS * PITCH];

    const int tid = threadIdx.x;
    const int w   = tid >> 6;
    const int l   = tid & 63;
    const int dt_ = 16 * (w & 3) + (l & 15);   // detector within tile
    const int klr = 4 * (w >> 2) + (l >> 4);   // k residue 0..7
    const int a   = blockIdx.y;
    const int d0  = blockIdx.x * DET_TILE;

    const float theta = angles[a];
    const float c = cosf(theta);
    const float s = sinf(theta);
    const float ac = fabsf(c), as = fabsf(s);
    const float cx = (W - 1) * 0.5f;            // 255.5
    const float cy = (H - 1) * 0.5f;            // 255.5
    const float t_off = (N_STEPS - 1) * 0.5f;   // 362

    const float u   = (float)(d0 + dt_) - (N_DET - 1) * 0.5f;
    const float bxu = cx - s * u;               // px = c*t + bxu
    const float byu = cy + c * u;               // py = s*t + byu

    // ---- conservative block k-window via interval arithmetic over u ----
    const float uLo = (float)d0 - (N_DET - 1) * 0.5f;
    const float uHi = uLo + (DET_TILE - 1);
    float su0 = s * uLo, su1 = s * uHi;
    float smin = fminf(su0, su1), smax = fmaxf(su0, su1);
    float cu0 = c * uLo, cu1 = c * uHi;
    float cmin = fminf(cu0, cu1), cmax = fmaxf(cu0, cu1);

    float tmin = -1e30f, tmax = 1e30f;
    {   // exists u: px in (-1, W)  <=>  c*t in (xlo, xhi)
        float xlo = -1.0f - cx + smin;
        float xhi = (float)W - cx + smax;
        if (ac > 1e-12f) {
            float t0 = xlo / c, t1 = xhi / c;
            tmin = fmaxf(tmin, fminf(t0, t1));
            tmax = fminf(tmax, fmaxf(t0, t1));
        } else if (xlo > 0.0f || xhi < 0.0f) {
            tmax = -2e30f;
        }
    }
    {   // exists u: py in (-1, H)  <=>  s*t in (ylo, yhi)
        float ylo = -1.0f - cy - cmax;
        float yhi = (float)H - cy - cmin;
        if (as > 1e-12f) {
            float t0 = ylo / s, t1 = yhi / s;
            tmin = fmaxf(tmin, fminf(t0, t1));
            tmax = fminf(tmax, fmaxf(t0, t1));
        } else if (ylo > 0.0f || yhi < 0.0f) {
            tmax = -2e30f;
        }
    }
    const int kminU = (int)fminf(725.0f, fmaxf(0.0f, ceilf(tmin + t_off) - 1.0f));
    const int kmaxU = (int)fmaxf(-1.0f, fminf((float)(N_STEPS - 1), floorf(tmax + t_off) + 1.0f));

    const float ucf = uLo + 0.5f * (DET_TILE - 1);
    const v2f dinc = {8.0f * c, 8.0f * s};

    float acc = 0.0f;

    for (int k0 = kminU; k0 <= kmaxU; k0 += K_TILE) {
        const int k1 = min(k0 + K_TILE - 1, kmaxU);
        // ---- bbox of ALL sample positions for (u in tile, t in [t0,t1]) ----
        const float t0f = (float)k0 - t_off;
        const float dt  = (float)(k1 - k0);
        const float tc  = t0f + 0.5f * dt;
        const float xc_ = fmaf(c, tc, cx) - s * ucf;
        const float yc_ = fmaf(s, tc, cy) + c * ucf;
        const float hx = fmaf(0.5f * ac, dt, 0.5f * (DET_TILE - 1) * as) + 0.5f;
        const float hy = fmaf(0.5f * as, dt, 0.5f * (DET_TILE - 1) * ac) + 0.5f;
        const int x0 = ((int)floorf(xc_ - hx)) & ~1;     // even -> 8B-aligned pairs
        const int y0 = (int)floorf(yc_ - hy);
        // cell row r covers image rows y0+r, y0+r+1; max yi = floor(yc+hy)
        const int bh = min((int)floorf(yc_ + hy) - y0 + 1, ROWS);

        // ---- stage: build f16 vertical-pair cells, 0 outside the image ----
        {
            const int total = bh * CHUNKS;
            for (int i = tid; i < total; i += 512) {
                int r  = i / CHUNKS;                // const-divisor magic mul
                int ch = i - r * CHUNKS;
                int gx = x0 + 2 * ch;
                int gy = y0 + r;
                float2 va = make_float2(0.0f, 0.0f);  // row gy   at gx, gx+1
                float2 vb = make_float2(0.0f, 0.0f);  // row gy+1 at gx, gx+1
                const bool ina = (unsigned)gy < (unsigned)H;
                const bool inb = (unsigned)(gy + 1) < (unsigned)H;
                const float* rowa = img + gy * W;
                if (gx >= 0 && gx + 1 < W) {
                    if (ina) va = *(const float2*)(rowa + gx);
                    if (inb) vb = *(const float2*)(rowa + W + gx);
                } else {
                    if ((unsigned)gx < (unsigned)W) {
                        if (ina) va.x = rowa[gx];
                        if (inb) vb.x = rowa[W + gx];
                    }
                    if ((unsigned)(gx + 1) < (unsigned)W) {
                        if (ina) va.y = rowa[gx + 1];
                        if (inb) vb.y = rowa[W + gx + 1];
                    }
                }
                PackU p0, p1;
                p0.h = __builtin_amdgcn_cvt_pkrtz(va.x, vb.x);  // (img[y][x], img[y+1][x])
                p1.h = __builtin_amdgcn_cvt_pkrtz(va.y, vb.y);
                uint2 w2 = make_uint2(p0.u, p1.u);
                *(uint2*)(tile + r * PITCH + 2 * ch) = w2;       // 8B aligned
            }
        }
        __syncthreads();

        // ---- branch-free sampling: 1 x ds_read2_b32 per sample ----
        // px,py >= 0 by bbox construction -> truncation == floor, fract valid
        const int kst = k0 + klr;
        v2f pos = {fmaf(c, (float)kst - t_off, bxu) - (float)x0,
                   fmaf(s, (float)kst - t_off, byu) - (float)y0};
        #pragma unroll 4
        for (int k = kst; k <= k1; k += 8) {
            int xi = (int)pos.x;
            int yi = (int)pos.y;
            float wx = __builtin_amdgcn_fractf(pos.x);
            float wy = __builtin_amdgcn_fractf(pos.y);
            int idx = __mul24(yi, PITCH) + xi;
            PackU a0, a1;
            a0.u = tile[idx];                    // ds_read2_b32 (0,1)
            a1.u = tile[idx + 1];
            v2f c0 = {(float)a0.h.x, (float)a0.h.y};   // (v00, v10)
            v2f c1 = {(float)a1.h.x, (float)a1.h.y};   // (v01, v11)
            v2f diff = c1 - c0;
            v2f wx2 = {wx, wx};
            v2f tb = __builtin_elementwise_fma(wx2, diff, c0);  // (top, bot)
            acc = fmaf(wy, tb.y - tb.x, acc + tb.x);
            pos += dinc;
        }
        __syncthreads();
    }

    // ---- reduce 8 k-residues per detector ----
    acc += __shfl_xor(acc, 16);
    acc += __shfl_xor(acc, 32);
    float* scratch = (float*)tile;
    if (l < 16) scratch[w * 16 + l] = acc;
    __syncthreads();
    if (tid < DET_TILE) {
        int g  = tid >> 4;
        int dd = tid & 15;
        float r = scratch[g * 16 + dd] + scratch[(g + 4) * 16 + dd];
        int dglob = d0 + tid;
        if (dglob < N_DET) sino[a * N_DET + dglob] = r;   // dets 736..767 phantom
    }
}

// ---------------------------------------------------------------------------
extern "C" void kernel_launch(void* const* d_in, const int* in_sizes, int n_in,
                              void* d_out, int out_size, void* d_ws, size_t ws_size,
                              hipStream_t stream) {
    const float* x      = (const float*)d_in[0];
    const float* reco   = (const float*)d_in[1];
    const float* angles = (const float*)d_in[2];

    float* sino    = (float*)d_out;              // (360, 736)
    float* updated = (float*)d_out + SINO_SIZE;  // (512, 512)

    int n4 = (H * W) / 4;
    add_kernel<<<n4 / 256, 256, 0, stream>>>(
        (const float4*)x, (const float4*)reco, (float4*)updated);

    dim3 grid((N_DET + DET_TILE - 1) / DET_TILE, N_ANGLES);   // (12, 360)
    radon_kernel<<<grid, 512, 0, stream>>>(updated, angles, sino);
}

// Round 12
// 96.177 us; speedup vs baseline: 1.9529x; 1.9529x over previous
//
#include <hip/hip_runtime.h>
#include <math.h>

constexpr int H = 512, W = 512;
constexpr int N_ANGLES = 360;
constexpr int N_DET = 736;
constexpr int N_STEPS = 725;                 // ceil(hypot(512,512))
constexpr int SINO_SIZE = N_ANGLES * N_DET;  // 264960

constexpr int DET_TILE = 64;
constexpr int K_TILE   = 64;
constexpr int PITCH    = 100;  // dwords; mult of 4 (16B chunks); need <= 97
constexpr int ROWS     = 93;   // need <= 93 (bh <= 2*45.05+3)
constexpr int QCHUNKS  = PITCH / 4;          // 25 float4 chunks/row (padded path)
constexpr int CHUNKS2  = PITCH / 2;          // 50 float2 chunks/row (fallback path)
constexpr int MAXJ     = 5;                  // ceil(93*25/512)
// LDS: 93*100*4 = 37200 B -> 4 blocks/CU @ 512 thr

// padded image (in d_ws): global (x,y) -> padded (x+PADX, y+PADY), zeros border
constexpr int PADX = 96, PADY = 96;
constexpr int PW = 720;   // x0 in [-92, 512] -> cols 4 .. 611+96=707 <= 719
constexpr int PH = 704;   // y0 in [-92, 512] -> rows 4 .. 604+96=700 <= 703
constexpr size_t PAD_BYTES = (size_t)PW * PH * 4;

typedef float v2f __attribute__((ext_vector_type(2)));

// ---------------------------------------------------------------------------
// Kernel 1a (padded path): padded = zero-bordered (x + reco); also writes the
// `updated` output. One thread per padded pixel.
// ---------------------------------------------------------------------------
__global__ void pad_kernel(const float* __restrict__ x,
                           const float* __restrict__ reco,
                           float* __restrict__ padded,
                           float* __restrict__ updated) {
    int i = blockIdx.x * blockDim.x + threadIdx.x;
    if (i >= PW * PH) return;
    int p = i / PW, q = i - p * PW;
    int gy = p - PADY, gx = q - PADX;
    float v = 0.0f;
    if ((unsigned)gy < (unsigned)H && (unsigned)gx < (unsigned)W) {
        int gi = gy * W + gx;
        v = x[gi] + reco[gi];
        updated[gi] = v;
    }
    padded[i] = v;
}

// ---------------------------------------------------------------------------
// Kernel 1b (fallback path): updated = x + reco
// ---------------------------------------------------------------------------
__global__ void add_kernel(const float4* __restrict__ x,
                           const float4* __restrict__ reco,
                           float4* __restrict__ out) {
    int i = blockIdx.x * blockDim.x + threadIdx.x;
    float4 a = x[i];
    float4 b = reco[i];
    out[i] = make_float4(a.x + b.x, a.y + b.y, a.z + b.z, a.w + b.w);
}

// ---------------------------------------------------------------------------
// Kernel 2: forward projection (r4/r7 proven geometry).
// Block = (angle, 64 detectors), 512 threads; wave footprint 16 det x 4 k.
// PADDED=true: stage via global_load_lds width-16 from the zero-padded image
//   (no boundary logic, no VGPR round-trip, ~5 instr per k-tile per thread).
// PADDED=false: r7 float2 staging from the raw image (bounds-checked).
// Sampling: branch-free, 2x ds_read2_b32 + packed-f32 lerp (r7 verbatim).
// ---------------------------------------------------------------------------
template <bool PADDED>
__global__ __launch_bounds__(512, 8) void radon_kernel(const float* __restrict__ img,
                                                       const float* __restrict__ angles,
                                                       float* __restrict__ sino) {
    __shared__ float tile[ROWS * PITCH];

    const int tid = threadIdx.x;
    const int w   = tid >> 6;
    const int l   = tid & 63;
    const int dt_ = 16 * (w & 3) + (l & 15);   // detector within tile
    const int klr = 4 * (w >> 2) + (l >> 4);   // k residue 0..7
    const int a   = blockIdx.y;
    const int d0  = blockIdx.x * DET_TILE;

    const float theta = angles[a];
    const float c = cosf(theta);
    const float s = sinf(theta);
    const float ac = fabsf(c), as = fabsf(s);
    const float cx = (W - 1) * 0.5f;            // 255.5
    const float cy = (H - 1) * 0.5f;            // 255.5
    const float t_off = (N_STEPS - 1) * 0.5f;   // 362

    const float u   = (float)(d0 + dt_) - (N_DET - 1) * 0.5f;
    const float bxu = cx - s * u;               // px = c*t + bxu
    const float byu = cy + c * u;               // py = s*t + byu

    // ---- conservative block k-window via interval arithmetic over u ----
    const float uLo = (float)d0 - (N_DET - 1) * 0.5f;
    const float uHi = uLo + (DET_TILE - 1);
    float su0 = s * uLo, su1 = s * uHi;
    float smin = fminf(su0, su1), smax = fmaxf(su0, su1);
    float cu0 = c * uLo, cu1 = c * uHi;
    float cmin = fminf(cu0, cu1), cmax = fmaxf(cu0, cu1);

    float tmin = -1e30f, tmax = 1e30f;
    {   // exists u: px in (-1, W)  <=>  c*t in (xlo, xhi)
        float xlo = -1.0f - cx + smin;
        float xhi = (float)W - cx + smax;
        if (ac > 1e-12f) {
            float t0 = xlo / c, t1 = xhi / c;
            tmin = fmaxf(tmin, fminf(t0, t1));
            tmax = fminf(tmax, fmaxf(t0, t1));
        } else if (xlo > 0.0f || xhi < 0.0f) {
            tmax = -2e30f;
        }
    }
    {   // exists u: py in (-1, H)  <=>  s*t in (ylo, yhi)
        float ylo = -1.0f - cy - cmax;
        float yhi = (float)H - cy - cmin;
        if (as > 1e-12f) {
            float t0 = ylo / s, t1 = yhi / s;
            tmin = fmaxf(tmin, fminf(t0, t1));
            tmax = fminf(tmax, fmaxf(t0, t1));
        } else if (ylo > 0.0f || yhi < 0.0f) {
            tmax = -2e30f;
        }
    }
    const int kminU = (int)fminf(725.0f, fmaxf(0.0f, ceilf(tmin + t_off) - 1.0f));
    const int kmaxU = (int)fmaxf(-1.0f, fminf((float)(N_STEPS - 1), floorf(tmax + t_off) + 1.0f));

    const float ucf = uLo + 0.5f * (DET_TILE - 1);
    const v2f dinc = {8.0f * c, 8.0f * s};

    float acc = 0.0f;

    for (int k0 = kminU; k0 <= kmaxU; k0 += K_TILE) {
        const int k1 = min(k0 + K_TILE - 1, kmaxU);
        // ---- bbox of ALL sample positions for (u in tile, t in [t0,t1]) ----
        const float t0f = (float)k0 - t_off;
        const float dt  = (float)(k1 - k0);
        const float tc  = t0f + 0.5f * dt;
        const float xc_ = fmaf(c, tc, cx) - s * ucf;
        const float yc_ = fmaf(s, tc, cy) + c * ucf;
        const float hx = fmaf(0.5f * ac, dt, 0.5f * (DET_TILE - 1) * as) + 0.5f;
        const float hy = fmaf(0.5f * as, dt, 0.5f * (DET_TILE - 1) * ac) + 0.5f;
        const int x0 = ((int)floorf(xc_ - hx)) & ~3;     // 16B-chunk aligned
        const int y0 = (int)floorf(yc_ - hy);
        const int bh = min((int)floorf(yc_ + hy) + 1 - y0 + 1, ROWS);

        // ---- stage bh rows x PITCH cols ----
        if constexpr (PADDED) {
            // async DMA: per-lane global src (always in-bounds of padded img),
            // wave-uniform LDS base + lane*16 (flat layout matches exactly).
            const int total = bh * QCHUNKS;
            const float* srow = img + (size_t)(y0 + PADY) * PW + (x0 + PADX);
            #pragma unroll
            for (int j = 0; j < MAXJ; ++j) {
                const int i = tid + j * 512;
                if (i < total) {
                    const int r  = i / QCHUNKS;          // const-divisor magic mul
                    const int ch = i - r * QCHUNKS;
                    const float* src = srow + r * PW + ch * 4;
                    float* dst = tile + (size_t)(i & ~63) * 4;  // wave-uniform
                    __builtin_amdgcn_global_load_lds(
                        (const __attribute__((address_space(1))) unsigned*)src,
                        (__attribute__((address_space(3))) unsigned*)dst,
                        16, 0, 0);
                }
            }
        } else {
            const int total = bh * CHUNKS2;
            for (int i = tid; i < total; i += 512) {
                int r  = i / CHUNKS2;
                int ch = i - r * CHUNKS2;
                int gx = x0 + 2 * ch;
                int gy = y0 + r;
                float2 v = make_float2(0.0f, 0.0f);
                if ((unsigned)gy < (unsigned)H) {
                    const float* rowp = img + gy * W;
                    if (gx >= 0 && gx + 1 < W) {
                        v = *(const float2*)(rowp + gx);
                    } else {
                        if ((unsigned)gx < (unsigned)W)       v.x = rowp[gx];
                        if ((unsigned)(gx + 1) < (unsigned)W) v.y = rowp[gx + 1];
                    }
                }
                *(float2*)(tile + r * PITCH + 2 * ch) = v;
            }
        }
        __syncthreads();   // compiler drains vmcnt(0) before s_barrier

        // ---- branch-free sampling from LDS (packed-f32 lerp) ----
        // px,py >= 0 by bbox construction -> truncation == floor, fract valid
        const int kst = k0 + klr;
        v2f pos = {fmaf(c, (float)kst - t_off, bxu) - (float)x0,
                   fmaf(s, (float)kst - t_off, byu) - (float)y0};
        #pragma unroll 4
        for (int k = kst; k <= k1; k += 8) {
            int xi = (int)pos.x;
            int yi = (int)pos.y;
            float wx = __builtin_amdgcn_fractf(pos.x);
            float wy = __builtin_amdgcn_fractf(pos.y);
            int idx = __mul24(yi, PITCH) + xi;
            v2f c0 = {tile[idx],     tile[idx + PITCH]};      // ds_read2 (0,100)
            v2f c1 = {tile[idx + 1], tile[idx + PITCH + 1]};  // ds_read2 (1,101)
            v2f diff = c1 - c0;
            v2f wx2 = {wx, wx};
            v2f tb = __builtin_elementwise_fma(wx2, diff, c0);  // (top, bot)
            acc = fmaf(wy, tb.y - tb.x, acc + tb.x);
            pos += dinc;
        }
        __syncthreads();
    }

    // ---- reduce 8 k-residues per detector (r7 verbatim) ----
    acc += __shfl_xor(acc, 16);
    acc += __shfl_xor(acc, 32);
    float* scratch = tile;
    if (l < 16) scratch[w * 16 + l] = acc;
    __syncthreads();
    if (tid < DET_TILE) {
        int g  = tid >> 4;
        int dd = tid & 15;
        float r = scratch[g * 16 + dd] + scratch[(g + 4) * 16 + dd];
        int dglob = d0 + tid;
        if (dglob < N_DET) sino[a * N_DET + dglob] = r;   // dets 736..767 phantom
    }
}

// ---------------------------------------------------------------------------
extern "C" void kernel_launch(void* const* d_in, const int* in_sizes, int n_in,
                              void* d_out, int out_size, void* d_ws, size_t ws_size,
                              hipStream_t stream) {
    const float* x      = (const float*)d_in[0];
    const float* reco   = (const float*)d_in[1];
    const float* angles = (const float*)d_in[2];

    float* sino    = (float*)d_out;              // (360, 736)
    float* updated = (float*)d_out + SINO_SIZE;  // (512, 512)

    dim3 grid((N_DET + DET_TILE - 1) / DET_TILE, N_ANGLES);   // (12, 360)

    if (ws_size >= PAD_BYTES) {
        float* padded = (float*)d_ws;
        pad_kernel<<<(PW * PH + 255) / 256, 256, 0, stream>>>(x, reco, padded, updated);
        radon_kernel<true><<<grid, 512, 0, stream>>>(padded, angles, sino);
    } else {
        int n4 = (H * W) / 4;
        add_kernel<<<n4 / 256, 256, 0, stream>>>(
            (const float4*)x, (const float4*)reco, (float4*)updated);
        radon_kernel<false><<<grid, 512, 0, stream>>>(updated, angles, sino);
    }
}